// Round 6
// baseline (427.403 us; speedup 1.0000x reference)
//
#include <hip/hip_runtime.h>
#include <hip/hip_fp16.h>

// Problem constants (from reference)
constexpr int SRC = 2000000;      // SRC_SIZE
constexpr int NN  = 4000000;      // NUM_NEURONS
constexpr int TBL = 2 * SRC;      // table entries (4M, fp16 -> 8 MB)
constexpr int HALF_TBL = TBL / 2; // 2M entries = 4 MB = one XCD L2

typedef int v4i __attribute__((ext_vector_type(4)));

// Build one half of the table: tout[i] = (half)v[idx[i]], i in [0, SRC).
// Branchless, 16 entries/thread: 4x int4 index loads, 16 gathers all in
// flight, 2x uint4 packed stores (full lines, no RMW).
__global__ __launch_bounds__(256) void build_half(
    const float* __restrict__ v, const int* __restrict__ idx,
    __half* __restrict__ tout)
{
    const int groups = SRC / 16;   // 125,000
    const int stride = gridDim.x * blockDim.x;
    for (int i = blockIdx.x * blockDim.x + threadIdx.x; i < groups; i += stride) {
        const int base = i * 16;
        v4i c0 = __builtin_nontemporal_load(reinterpret_cast<const v4i*>(idx + base));
        v4i c1 = __builtin_nontemporal_load(reinterpret_cast<const v4i*>(idx + base + 4));
        v4i c2 = __builtin_nontemporal_load(reinterpret_cast<const v4i*>(idx + base + 8));
        v4i c3 = __builtin_nontemporal_load(reinterpret_cast<const v4i*>(idx + base + 12));
        float f0 = v[c0.x], f1 = v[c0.y], f2 = v[c0.z], f3 = v[c0.w];
        float f4 = v[c1.x], f5 = v[c1.y], f6 = v[c1.z], f7 = v[c1.w];
        float f8 = v[c2.x], f9 = v[c2.y], fa = v[c2.z], fb = v[c2.w];
        float fc = v[c3.x], fd = v[c3.y], fe = v[c3.z], ff = v[c3.w];
        #define PK(lo, hi) ((unsigned)__half_as_ushort(__float2half_rn(lo)) \
                          | ((unsigned)__half_as_ushort(__float2half_rn(hi)) << 16))
        uint4 o0 = { PK(f0, f1), PK(f2, f3), PK(f4, f5), PK(f6, f7) };
        uint4 o1 = { PK(f8, f9), PK(fa, fb), PK(fc, fd), PK(fe, ff) };
        #undef PK
        reinterpret_cast<uint4*>(tout + base)[0] = o0;
        reinterpret_cast<uint4*>(tout + base)[1] = o1;
    }
}

// Neuron stage, two phases for L2 residency of one 4 MB table half each.
// Branchless: out-of-phase indices are clamped to a single always-hot line
// (entry 0 of the phase's half) and their weight is zeroed. All 16 gathers
// (2 neurons) are independent -> one waitcnt, 16 requests in flight.
template<int PHASE>
__global__ __launch_bounds__(256) void neuron_pass(
    const int*    __restrict__ cidx,
    const __half* __restrict__ table,
    const float*  __restrict__ w,
    float*        __restrict__ po)   // partial (phase0 out / phase1 in+out) == d_out
{
    float wk[8];
    #pragma unroll
    for (int k = 0; k < 8; ++k) wk[k] = w[k];

    const int tid    = blockIdx.x * blockDim.x + threadIdx.x;
    const int stride = gridDim.x * blockDim.x;

    for (int n = tid; n < NN; n += 2 * stride) {
        const int n2   = n + stride;
        const bool has2 = (n2 < NN);
        const int m2   = has2 ? n2 : n;   // clamped (loads safe, store guarded)

        const v4i* pa = reinterpret_cast<const v4i*>(cidx) + (size_t)n  * 2;
        const v4i* pb = reinterpret_cast<const v4i*>(cidx) + (size_t)m2 * 2;
        v4i a0 = __builtin_nontemporal_load(pa);
        v4i a1 = __builtin_nontemporal_load(pa + 1);
        v4i b0 = __builtin_nontemporal_load(pb);
        v4i b1 = __builtin_nontemporal_load(pb + 1);

        // Branchless phase predication.
        #define SEL(c, k, cc, ww)                                            \
            const bool p_##cc = (PHASE == 0) ? ((c) < HALF_TBL)              \
                                             : ((c) >= HALF_TBL);            \
            const int   cc = p_##cc ? (c) : (PHASE == 0 ? 0 : HALF_TBL);     \
            const float ww = p_##cc ? wk[k] : 0.0f;
        SEL(a0.x, 0, ca0, wa0) SEL(a0.y, 1, ca1, wa1)
        SEL(a0.z, 2, ca2, wa2) SEL(a0.w, 3, ca3, wa3)
        SEL(a1.x, 4, ca4, wa4) SEL(a1.y, 5, ca5, wa5)
        SEL(a1.z, 6, ca6, wa6) SEL(a1.w, 7, ca7, wa7)
        SEL(b0.x, 0, cb0, wb0) SEL(b0.y, 1, cb1, wb1)
        SEL(b0.z, 2, cb2, wb2) SEL(b0.w, 3, cb3, wb3)
        SEL(b1.x, 4, cb4, wb4) SEL(b1.y, 5, cb5, wb5)
        SEL(b1.z, 6, cb6, wb6) SEL(b1.w, 7, cb7, wb7)
        #undef SEL

        // 16 independent gathers, all issued before any use.
        const __half ga0 = table[ca0], ga1 = table[ca1], ga2 = table[ca2], ga3 = table[ca3];
        const __half ga4 = table[ca4], ga5 = table[ca5], ga6 = table[ca6], ga7 = table[ca7];
        const __half gb0 = table[cb0], gb1 = table[cb1], gb2 = table[cb2], gb3 = table[cb3];
        const __half gb4 = table[cb4], gb5 = table[cb5], gb6 = table[cb6], gb7 = table[cb7];

        float accA = (PHASE == 0) ? 0.0f : __builtin_nontemporal_load(&po[n]);
        float accB = (PHASE == 0) ? 0.0f : __builtin_nontemporal_load(&po[m2]);

        accA += __half2float(ga0) * wa0 + __half2float(ga1) * wa1
              + __half2float(ga2) * wa2 + __half2float(ga3) * wa3
              + __half2float(ga4) * wa4 + __half2float(ga5) * wa5
              + __half2float(ga6) * wa6 + __half2float(ga7) * wa7;
        accB += __half2float(gb0) * wb0 + __half2float(gb1) * wb1
              + __half2float(gb2) * wb2 + __half2float(gb3) * wb3
              + __half2float(gb4) * wb4 + __half2float(gb5) * wb5
              + __half2float(gb6) * wb6 + __half2float(gb7) * wb7;

        if (PHASE == 0) {
            __builtin_nontemporal_store(accA, &po[n]);
            if (has2) __builtin_nontemporal_store(accB, &po[n2]);
        } else {
            __builtin_nontemporal_store(tanhf(accA), &po[n]);
            if (has2) __builtin_nontemporal_store(tanhf(accB), &po[n2]);
        }
    }
}

// Fallback (ws too small): fused double-gather, full f32.
__global__ __launch_bounds__(256) void fused_kernel(
    const float* __restrict__ va, const float* __restrict__ vb,
    const int*   __restrict__ ia, const int*   __restrict__ ib,
    const int*   __restrict__ cidx,
    const float* __restrict__ w,
    float* __restrict__ out)
{
    __shared__ float ws[8];
    if (threadIdx.x < 8) ws[threadIdx.x] = w[threadIdx.x];
    __syncthreads();

    const int stride = gridDim.x * blockDim.x;
    for (int n = blockIdx.x * blockDim.x + threadIdx.x; n < NN; n += stride) {
        const int4* p = reinterpret_cast<const int4*>(cidx) + (size_t)n * 2;
        int4 c0 = p[0];
        int4 c1 = p[1];
        int c[8] = {c0.x, c0.y, c0.z, c0.w, c1.x, c1.y, c1.z, c1.w};
        float acc = 0.f;
        #pragma unroll
        for (int k = 0; k < 8; ++k) {
            int ci = c[k];
            float v = (ci < SRC) ? va[ia[ci]] : vb[ib[ci - SRC]];
            acc += v * ws[k];
        }
        out[n] = tanhf(acc);
    }
}

extern "C" void kernel_launch(void* const* d_in, const int* in_sizes, int n_in,
                              void* d_out, int out_size, void* d_ws, size_t ws_size,
                              hipStream_t stream) {
    const float* va   = (const float*)d_in[0];
    const float* vb   = (const float*)d_in[1];
    const float* w    = (const float*)d_in[2];
    const int*   ia   = (const int*)d_in[3];
    const int*   ib   = (const int*)d_in[4];
    const int*   cidx = (const int*)d_in[5];
    float* out = (float*)d_out;

    const size_t table_bytes = (size_t)TBL * sizeof(__half);  // 8 MB
    if (ws_size >= table_bytes) {
        __half* table = (__half*)d_ws;
        build_half<<<512, 256, 0, stream>>>(va, ia, table);
        build_half<<<512, 256, 0, stream>>>(vb, ib, table + SRC);
        neuron_pass<0><<<2048, 256, 0, stream>>>(cidx, table, w, out);
        neuron_pass<1><<<2048, 256, 0, stream>>>(cidx, table, w, out);
    } else {
        fused_kernel<<<2048, 256, 0, stream>>>(va, vb, ia, ib, cidx, w, out);
    }
}

// Round 9
// 425.650 us; speedup vs baseline: 1.0041x; 1.0041x over previous
//
#include <hip/hip_runtime.h>
#include <hip/hip_fp16.h>

// Problem constants (from reference)
constexpr int SRC = 2000000;      // SRC_SIZE
constexpr int NN  = 4000000;      // NUM_NEURONS
constexpr int TBL = 2 * SRC;      // table entries (4M, fp16 -> 8 MB)
constexpr int HALF_TBL = TBL / 2; // 2M entries = 4 MB = one XCD L2
constexpr int HS = SRC / 2;       // 1M: source-value chunk boundary (4 MB of f32)

typedef int v4i __attribute__((ext_vector_type(4)));
typedef unsigned int uint;
typedef uint v4u __attribute__((ext_vector_type(4)));   // nontemporal-compatible

// ---------------------------------------------------------------------------
// Build stage, L2-chunked like the neuron stage.
// Per source half (va or vb), two sub-passes over idx[0..SRC):
//   LO pass: gather v[min(c, HS-1)]  — all requests land in v[0..HS) = 4 MB,
//            L2-resident; pack 8 fp16 -> v4u full-line store.
//   HI pass: gather v[max(c, HS)]    — requests land in v[HS..SRC) = 4 MB;
//            read LO's packed output, per-entry select, full-line store.
// Branchless, no partial-line writes, 8 gathers in flight per thread.
// ---------------------------------------------------------------------------
__global__ __launch_bounds__(256) void build_lo(
    const float* __restrict__ v, const int* __restrict__ idx,
    __half* __restrict__ tout)
{
    const int groups = SRC / 8;   // 250,000 groups of 8 entries
    const int stride = gridDim.x * blockDim.x;
    for (int i = blockIdx.x * blockDim.x + threadIdx.x; i < groups; i += stride) {
        const int base = i * 8;
        v4i c0 = __builtin_nontemporal_load(reinterpret_cast<const v4i*>(idx + base));
        v4i c1 = __builtin_nontemporal_load(reinterpret_cast<const v4i*>(idx + base + 4));
        int d0 = min(c0.x, HS - 1), d1 = min(c0.y, HS - 1);
        int d2 = min(c0.z, HS - 1), d3 = min(c0.w, HS - 1);
        int d4 = min(c1.x, HS - 1), d5 = min(c1.y, HS - 1);
        int d6 = min(c1.z, HS - 1), d7 = min(c1.w, HS - 1);
        float f0 = v[d0], f1 = v[d1], f2 = v[d2], f3 = v[d3];
        float f4 = v[d4], f5 = v[d5], f6 = v[d6], f7 = v[d7];
        #define PK(lo, hi) ((uint)__half_as_ushort(__float2half_rn(lo)) \
                          | ((uint)__half_as_ushort(__float2half_rn(hi)) << 16))
        v4u o = { PK(f0, f1), PK(f2, f3), PK(f4, f5), PK(f6, f7) };
        #undef PK
        __builtin_nontemporal_store(o, reinterpret_cast<v4u*>(tout) + i);
    }
}

__global__ __launch_bounds__(256) void build_hi(
    const float* __restrict__ v, const int* __restrict__ idx,
    __half* __restrict__ tout)
{
    const int groups = SRC / 8;
    const int stride = gridDim.x * blockDim.x;
    for (int i = blockIdx.x * blockDim.x + threadIdx.x; i < groups; i += stride) {
        const int base = i * 8;
        v4i c0 = __builtin_nontemporal_load(reinterpret_cast<const v4i*>(idx + base));
        v4i c1 = __builtin_nontemporal_load(reinterpret_cast<const v4i*>(idx + base + 4));
        int d0 = max(c0.x, HS), d1 = max(c0.y, HS);
        int d2 = max(c0.z, HS), d3 = max(c0.w, HS);
        int d4 = max(c1.x, HS), d5 = max(c1.y, HS);
        int d6 = max(c1.z, HS), d7 = max(c1.w, HS);
        float f0 = v[d0], f1 = v[d1], f2 = v[d2], f3 = v[d3];
        float f4 = v[d4], f5 = v[d5], f6 = v[d6], f7 = v[d7];
        v4u prior = __builtin_nontemporal_load(reinterpret_cast<const v4u*>(tout) + i);
        // Per-entry select: keep LO value when c < HS, else HI gather.
        #define HB(f) ((uint)__half_as_ushort(__float2half_rn(f)))
        uint h0 = (c0.x < HS) ? (prior.x & 0xFFFFu)  : HB(f0);
        uint h1 = (c0.y < HS) ? (prior.x >> 16)      : HB(f1);
        uint h2 = (c0.z < HS) ? (prior.y & 0xFFFFu)  : HB(f2);
        uint h3 = (c0.w < HS) ? (prior.y >> 16)      : HB(f3);
        uint h4 = (c1.x < HS) ? (prior.z & 0xFFFFu)  : HB(f4);
        uint h5 = (c1.y < HS) ? (prior.z >> 16)      : HB(f5);
        uint h6 = (c1.z < HS) ? (prior.w & 0xFFFFu)  : HB(f6);
        uint h7 = (c1.w < HS) ? (prior.w >> 16)      : HB(f7);
        #undef HB
        v4u o = { h0 | (h1 << 16), h2 | (h3 << 16),
                  h4 | (h5 << 16), h6 | (h7 << 16) };
        __builtin_nontemporal_store(o, reinterpret_cast<v4u*>(tout) + i);
    }
}

// ---------------------------------------------------------------------------
// Neuron stage, two phases for L2 residency of one 4 MB table half each
// (unchanged from round 6 — measured at ~the L2 service floor).
// ---------------------------------------------------------------------------
template<int PHASE>
__global__ __launch_bounds__(256) void neuron_pass(
    const int*    __restrict__ cidx,
    const __half* __restrict__ table,
    const float*  __restrict__ w,
    float*        __restrict__ po)   // partial (phase0 out / phase1 in+out) == d_out
{
    float wk[8];
    #pragma unroll
    for (int k = 0; k < 8; ++k) wk[k] = w[k];

    const int tid    = blockIdx.x * blockDim.x + threadIdx.x;
    const int stride = gridDim.x * blockDim.x;

    for (int n = tid; n < NN; n += 2 * stride) {
        const int n2   = n + stride;
        const bool has2 = (n2 < NN);
        const int m2   = has2 ? n2 : n;

        const v4i* pa = reinterpret_cast<const v4i*>(cidx) + (size_t)n  * 2;
        const v4i* pb = reinterpret_cast<const v4i*>(cidx) + (size_t)m2 * 2;
        v4i a0 = __builtin_nontemporal_load(pa);
        v4i a1 = __builtin_nontemporal_load(pa + 1);
        v4i b0 = __builtin_nontemporal_load(pb);
        v4i b1 = __builtin_nontemporal_load(pb + 1);

        #define SEL(c, k, cc, ww)                                            \
            const bool p_##cc = (PHASE == 0) ? ((c) < HALF_TBL)              \
                                             : ((c) >= HALF_TBL);            \
            const int   cc = p_##cc ? (c) : (PHASE == 0 ? 0 : HALF_TBL);     \
            const float ww = p_##cc ? wk[k] : 0.0f;
        SEL(a0.x, 0, ca0, wa0) SEL(a0.y, 1, ca1, wa1)
        SEL(a0.z, 2, ca2, wa2) SEL(a0.w, 3, ca3, wa3)
        SEL(a1.x, 4, ca4, wa4) SEL(a1.y, 5, ca5, wa5)
        SEL(a1.z, 6, ca6, wa6) SEL(a1.w, 7, ca7, wa7)
        SEL(b0.x, 0, cb0, wb0) SEL(b0.y, 1, cb1, wb1)
        SEL(b0.z, 2, cb2, wb2) SEL(b0.w, 3, cb3, wb3)
        SEL(b1.x, 4, cb4, wb4) SEL(b1.y, 5, cb5, wb5)
        SEL(b1.z, 6, cb6, wb6) SEL(b1.w, 7, cb7, wb7)
        #undef SEL

        const __half ga0 = table[ca0], ga1 = table[ca1], ga2 = table[ca2], ga3 = table[ca3];
        const __half ga4 = table[ca4], ga5 = table[ca5], ga6 = table[ca6], ga7 = table[ca7];
        const __half gb0 = table[cb0], gb1 = table[cb1], gb2 = table[cb2], gb3 = table[cb3];
        const __half gb4 = table[cb4], gb5 = table[cb5], gb6 = table[cb6], gb7 = table[cb7];

        float accA = (PHASE == 0) ? 0.0f : __builtin_nontemporal_load(&po[n]);
        float accB = (PHASE == 0) ? 0.0f : __builtin_nontemporal_load(&po[m2]);

        accA += __half2float(ga0) * wa0 + __half2float(ga1) * wa1
              + __half2float(ga2) * wa2 + __half2float(ga3) * wa3
              + __half2float(ga4) * wa4 + __half2float(ga5) * wa5
              + __half2float(ga6) * wa6 + __half2float(ga7) * wa7;
        accB += __half2float(gb0) * wb0 + __half2float(gb1) * wb1
              + __half2float(gb2) * wb2 + __half2float(gb3) * wb3
              + __half2float(gb4) * wb4 + __half2float(gb5) * wb5
              + __half2float(gb6) * wb6 + __half2float(gb7) * wb7;

        if (PHASE == 0) {
            __builtin_nontemporal_store(accA, &po[n]);
            if (has2) __builtin_nontemporal_store(accB, &po[n2]);
        } else {
            __builtin_nontemporal_store(tanhf(accA), &po[n]);
            if (has2) __builtin_nontemporal_store(tanhf(accB), &po[n2]);
        }
    }
}

// Fallback (ws too small): fused double-gather, full f32.
__global__ __launch_bounds__(256) void fused_kernel(
    const float* __restrict__ va, const float* __restrict__ vb,
    const int*   __restrict__ ia, const int*   __restrict__ ib,
    const int*   __restrict__ cidx,
    const float* __restrict__ w,
    float* __restrict__ out)
{
    __shared__ float ws[8];
    if (threadIdx.x < 8) ws[threadIdx.x] = w[threadIdx.x];
    __syncthreads();

    const int stride = gridDim.x * blockDim.x;
    for (int n = blockIdx.x * blockDim.x + threadIdx.x; n < NN; n += stride) {
        const int4* p = reinterpret_cast<const int4*>(cidx) + (size_t)n * 2;
        int4 c0 = p[0];
        int4 c1 = p[1];
        int c[8] = {c0.x, c0.y, c0.z, c0.w, c1.x, c1.y, c1.z, c1.w};
        float acc = 0.f;
        #pragma unroll
        for (int k = 0; k < 8; ++k) {
            int ci = c[k];
            float v = (ci < SRC) ? va[ia[ci]] : vb[ib[ci - SRC]];
            acc += v * ws[k];
        }
        out[n] = tanhf(acc);
    }
}

extern "C" void kernel_launch(void* const* d_in, const int* in_sizes, int n_in,
                              void* d_out, int out_size, void* d_ws, size_t ws_size,
                              hipStream_t stream) {
    const float* va   = (const float*)d_in[0];
    const float* vb   = (const float*)d_in[1];
    const float* w    = (const float*)d_in[2];
    const int*   ia   = (const int*)d_in[3];
    const int*   ib   = (const int*)d_in[4];
    const int*   cidx = (const int*)d_in[5];
    float* out = (float*)d_out;

    const size_t table_bytes = (size_t)TBL * sizeof(__half);  // 8 MB
    if (ws_size >= table_bytes) {
        __half* table = (__half*)d_ws;
        build_lo<<<1024, 256, 0, stream>>>(va, ia, table);
        build_hi<<<1024, 256, 0, stream>>>(va, ia, table);
        build_lo<<<1024, 256, 0, stream>>>(vb, ib, table + SRC);
        build_hi<<<1024, 256, 0, stream>>>(vb, ib, table + SRC);
        neuron_pass<0><<<2048, 256, 0, stream>>>(cidx, table, w, out);
        neuron_pass<1><<<2048, 256, 0, stream>>>(cidx, table, w, out);
    } else {
        fused_kernel<<<2048, 256, 0, stream>>>(va, vb, ia, ib, cidx, w, out);
    }
}